// Round 3
// baseline (1096.806 us; speedup 1.0000x reference)
//
#include <hip/hip_runtime.h>
#include <cstdint>
#include <cstddef>

// Conv2d 3x3 s1 p1: N=16, CI=64, CO=128, H=W=224, fp32 in/out.
// v3: v2 structure (bf16 xp pre-pack + global_load_lds staging + MFMA) with a
// rewritten epilogue: per-wave LDS transpose so global stores are contiguous
// float4 runs (full-line writes, no RMW/RFO inflation). No nontemporal.

typedef short bf16x8 __attribute__((ext_vector_type(8)));
typedef float f32x4 __attribute__((ext_vector_type(4)));

#define N_ 16
#define CI_ 64
#define CO_ 128
#define H_ 224
#define W_ 224
#define HW_ (H_ * W_)

// xp strides in shorts
#define WP_ 226
#define CBS_ 1808ULL        // WP_*8
#define HPS_ 14464ULL       // 8*CBS_
#define NS_ 3268864ULL      // 226*HPS_

__device__ __forceinline__ unsigned short f2bf(float f) {
    unsigned u = __builtin_bit_cast(unsigned, f);
    u += 0x7FFFu + ((u >> 16) & 1u);   // round-to-nearest-even
    return (unsigned short)(u >> 16);
}

// weight [CO][CI][3][3] fp32 -> wr[t][co][ci] bf16  (t = kh*3+kw)
__global__ void prep_weight(const float* __restrict__ w, unsigned short* __restrict__ wr) {
    int i = blockIdx.x * 256 + threadIdx.x;          // i = t*8192 + co*64 + ci
    if (i >= 9 * CO_ * CI_) return;
    int ci = i & 63;
    int co = (i >> 6) & 127;
    int t  = i >> 13;
    wr[i] = f2bf(w[(co * CI_ + ci) * 9 + t]);
}

// x[n][ci][h][w] fp32 -> xp[n][hp][cb][wp][c8] bf16, halos (hp 0/225, wp 0/225) zero.
__global__ __launch_bounds__(256) void prep_x(const float* __restrict__ x,
                                              unsigned short* __restrict__ xp) {
    int b = blockIdx.x;                 // 16*226
    int n = b / 226, hp = b - n * 226;
    int tid = threadIdx.x;
    unsigned short* row = xp + (size_t)n * NS_ + (size_t)hp * HPS_;
    if (hp == 0 || hp == 225) {
        #pragma unroll
        for (int k = 0; k < 8; ++k) {
            int i = k * 256 + tid;
            if (i < 1808) ((uint4*)row)[i] = make_uint4(0, 0, 0, 0);
        }
        return;
    }
    int h = hp - 1;
    const float* xb = x + (size_t)n * CI_ * HW_ + (size_t)h * W_;
    for (int k = 0; k < 7; ++k) {
        int item = k * 256 + tid;       // 1792 = 8cb * 224w
        int w = item % 224;
        int cb = item / 224;
        unsigned r[4];
        #pragma unroll
        for (int c = 0; c < 4; ++c) {
            float lo = xb[(size_t)(cb * 8 + 2 * c) * HW_ + w];
            float hi = xb[(size_t)(cb * 8 + 2 * c + 1) * HW_ + w];
            r[c] = (unsigned)f2bf(lo) | ((unsigned)f2bf(hi) << 16);
        }
        *(uint4*)(row + (size_t)cb * CBS_ + (size_t)(w + 1) * 8) = make_uint4(r[0], r[1], r[2], r[3]);
    }
    if (tid < 16) {
        int cb = tid >> 1, wp = (tid & 1) * 225;
        *(uint4*)(row + (size_t)cb * CBS_ + (size_t)wp * 8) = make_uint4(0, 0, 0, 0);
    }
}

// Main: one WG (512 thr, 8 waves) -> out[n][0:128][h0:h0+2][0:224].
__global__ __launch_bounds__(512, 4) void conv2(
    const unsigned short* __restrict__ xp, const unsigned short* __restrict__ wr,
    const float* __restrict__ bias, float* __restrict__ out)
{
    // compute phase:  xs[r(4)][cbl(4)][wp(226)][8 ci] bf16 = 57,856 B
    // epilogue phase: reused as float lf[8 waves][1808]   = 57,856 B
    __shared__ __align__(16) unsigned short xs[4 * 4 * 226 * 8];

    int bid = blockIdx.x;
    int swz = (bid & 7) * 224 + (bid >> 3);    // bijective: 1792 = 8*224
    int n = swz / 112;
    int hblk = swz - n * 112;
    int h0 = hblk * 2;

    int tid = threadIdx.x, lane = tid & 63, wid = tid >> 6;
    int hr = wid & 1, nh = (wid >> 1) & 1, mh = wid >> 2;
    int lrow = lane & 15, lk = lane >> 4;

    f32x4 acc[4][7];
    #pragma unroll
    for (int a = 0; a < 4; ++a)
        #pragma unroll
        for (int b2 = 0; b2 < 7; ++b2)
            #pragma unroll
            for (int k = 0; k < 4; ++k)
                acc[a][b2][k] = 0.0f;

    const unsigned short* xpn = xp + (size_t)n * NS_;

    for (int ch = 0; ch < 2; ++ch) {
        if (ch) __syncthreads();
        // ---- stage via global_load_lds: 16 runs of 226 x 16B, linear LDS ----
        #pragma unroll
        for (int rr = 0; rr < 2; ++rr) {
            int run = wid * 2 + rr;            // 0..15
            int r = run >> 2, cbl = run & 3;
            const unsigned short* src = xpn + (size_t)(h0 + r) * HPS_ + (size_t)(ch * 4 + cbl) * CBS_;
            unsigned short* dst = &xs[(size_t)(r * 4 + cbl) * (226 * 8)];
            #pragma unroll
            for (int c = 0; c < 4; ++c) {
                int chunk = c * 64 + lane;
                if (chunk < 226)
                    __builtin_amdgcn_global_load_lds(
                        (const __attribute__((address_space(1))) void*)(src + (size_t)chunk * 8),
                        (__attribute__((address_space(3))) void*)(dst + c * 512),
                        16, 0, 0);
            }
        }
        __syncthreads();

        // ---- 9 taps x K=32 ----
        #pragma unroll
        for (int t = 0; t < 9; ++t) {
            int kh = t / 3, kw = t - kh * 3;
            bf16x8 afr[4];
            #pragma unroll
            for (int mf = 0; mf < 4; ++mf) {
                size_t ai = ((size_t)(t * 128 + mh * 64 + mf * 16 + lrow)) * 64
                          + (size_t)(ch * 32 + lk * 8);
                afr[mf] = *(const bf16x8*)(wr + ai);
            }
            int rbase = ((hr + kh) * 4 + lk) * 226;
            int wpb = nh * 112 + lrow + kw;
            #pragma unroll
            for (int nf = 0; nf < 7; ++nf) {
                bf16x8 bfr = *(const bf16x8*)(&xs[(size_t)(rbase + wpb + nf * 16) * 8]);
                #pragma unroll
                for (int mf = 0; mf < 4; ++mf)
                    acc[mf][nf] = __builtin_amdgcn_mfma_f32_16x16x32_bf16(
                        afr[mf], bfr, acc[mf][nf], 0, 0, 0);
            }
        }
    }

    // ---- epilogue: per-wave LDS transpose -> contiguous float4 stores ----
    // wave region: lf[wid*1808 .. +1808) floats (7232 B, disjoint per wave).
    // layout: [lk(4) stride 452][r(4) stride 112][w_local(112)]
    __syncthreads();                       // all MFMA reads of xs done
    float* lf = (float*)xs;
    int h = h0 + hr;
    #pragma unroll
    for (int mf = 0; mf < 4; ++mf) {
        float bv[4];
        #pragma unroll
        for (int r = 0; r < 4; ++r)
            bv[r] = bias[mh * 64 + mf * 16 + lk * 4 + r];
        // write phase (wave-local; DS ops in-order per wave, no barrier needed)
        float* wbase = lf + wid * 1808 + lk * 452 + lrow;
        #pragma unroll
        for (int r = 0; r < 4; ++r)
            #pragma unroll
            for (int nf = 0; nf < 7; ++nf)
                wbase[r * 112 + nf * 16] = acc[mf][nf][r] + bv[r];
        // read + store phase: 7 x 64-lane float4 = contiguous full-line writes
        #pragma unroll
        for (int j = 0; j < 7; ++j) {
            int idx4 = j * 64 + lane;          // 0..447 (448 float4 per wave)
            int col = idx4 / 28;               // co_local 0..15
            int w4  = idx4 - col * 28;         // 0..27
            f32x4 v = *(const f32x4*)(lf + wid * 1808 + (col >> 2) * 452 + (col & 3) * 112 + w4 * 4);
            size_t ob = (((size_t)n * CO_ + mh * 64 + mf * 16 + col) * H_ + h) * W_
                      + nh * 112 + w4 * 4;
            *(f32x4*)(out + ob) = v;
        }
    }
}

// ---------------- round-1 fallback (used only if ws_size is small) ----------------
__global__ __launch_bounds__(512, 2) void conv_mfma(
    const float* __restrict__ x, const unsigned short* __restrict__ wr,
    const float* __restrict__ bias, float* __restrict__ out)
{
    __shared__ unsigned short xs[4 * 4 * 226 * 8];
    int bid = blockIdx.x;
    int swz = (bid & 7) * 224 + (bid >> 3);
    int n = swz / 112;
    int hblk = swz - n * 112;
    int h0 = hblk * 2;
    int tid = threadIdx.x;
    int lane = tid & 63;
    int wid = tid >> 6;
    int hr = wid & 1, nh = (wid >> 1) & 1, mh = wid >> 2;
    int lrow = lane & 15, lk = lane >> 4;

    f32x4 acc[4][7];
    #pragma unroll
    for (int a = 0; a < 4; ++a)
        #pragma unroll
        for (int b = 0; b < 7; ++b)
            #pragma unroll
            for (int k = 0; k < 4; ++k)
                acc[a][b][k] = 0.0f;

    for (int ch = 0; ch < 2; ++ch) {
        if (ch) __syncthreads();
        const float* xb = x + ((size_t)n * CI_ + (size_t)ch * 32) * HW_;
        int wcol = tid % 224;
        int rem = tid / 224;
        for (int it = 0; it < 7; ++it) {
            float v[8]; int bi[8];
            #pragma unroll
            for (int u = 0; u < 8; ++u) {
                int ciL = rem & 31;
                int r4 = rem >> 5;
                int hh = h0 - 1 + r4;
                float val = 0.0f;
                if ((unsigned)hh < (unsigned)H_)
                    val = xb[(size_t)ciL * HW_ + (size_t)hh * W_ + wcol];
                v[u] = val;
                bi[u] = (((r4 << 2) + (ciL >> 3)) * 226 + wcol + 1) * 8 + (ciL & 7);
                wcol += 64; rem += 2;
                if (wcol >= 224) { wcol -= 224; rem += 1; }
            }
            #pragma unroll
            for (int u = 0; u < 8; ++u)
                xs[bi[u]] = f2bf(v[u]);
        }
        if (tid < 256) {
            int wp = (tid & 1) * 225;
            int ciL = (tid >> 1) & 31;
            int r4 = tid >> 6;
            xs[(((r4 << 2) + (ciL >> 3)) * 226 + wp) * 8 + (ciL & 7)] = 0;
        }
        __syncthreads();

        #pragma unroll
        for (int t = 0; t < 9; ++t) {
            int kh = t / 3, kw = t - kh * 3;
            bf16x8 afr[4];
            #pragma unroll
            for (int mf = 0; mf < 4; ++mf) {
                size_t ai = ((size_t)(t * 128 + mh * 64 + mf * 16 + lrow)) * 64
                          + (size_t)(ch * 32 + lk * 8);
                afr[mf] = *(const bf16x8*)(wr + ai);
            }
            int rbase = ((hr + kh) * 4 + lk) * 226;
            int wpb = nh * 112 + lrow + kw;
            #pragma unroll
            for (int nf = 0; nf < 7; ++nf) {
                bf16x8 bfr = *(const bf16x8*)(&xs[(size_t)(rbase + wpb + nf * 16) * 8]);
                #pragma unroll
                for (int mf = 0; mf < 4; ++mf)
                    acc[mf][nf] = __builtin_amdgcn_mfma_f32_16x16x32_bf16(
                        afr[mf], bfr, acc[mf][nf], 0, 0, 0);
            }
        }
    }

    int h = h0 + hr;
    #pragma unroll
    for (int mf = 0; mf < 4; ++mf) {
        #pragma unroll
        for (int r = 0; r < 4; ++r) {
            int co = mh * 64 + mf * 16 + lk * 4 + r;
            float bv = bias[co];
            size_t ob = (((size_t)n * CO_ + co) * H_ + h) * W_ + nh * 112 + lrow;
            #pragma unroll
            for (int nf = 0; nf < 7; ++nf)
                out[ob + (size_t)nf * 16] = acc[mf][nf][r] + bv;
        }
    }
}

extern "C" void kernel_launch(void* const* d_in, const int* in_sizes, int n_in,
                              void* d_out, int out_size, void* d_ws, size_t ws_size,
                              hipStream_t stream) {
    const float* x    = (const float*)d_in[0];
    const float* w    = (const float*)d_in[1];
    const float* bias = (const float*)d_in[2];
    float* out = (float*)d_out;
    unsigned short* wr = (unsigned short*)d_ws;          // 147,456 B
    const size_t xp_bytes = (size_t)N_ * NS_ * 2;        // 104,603,648 B
    const size_t need = 147456 + xp_bytes;

    prep_weight<<<dim3(288), dim3(256), 0, stream>>>(w, wr);
    if (ws_size >= need) {
        unsigned short* xp = wr + 73728;                 // +147,456 B
        prep_x<<<dim3(16 * 226), dim3(256), 0, stream>>>(x, xp);
        conv2<<<dim3(16 * 112), dim3(512), 0, stream>>>(xp, wr, bias, out);
    } else {
        conv_mfma<<<dim3(16 * 112), dim3(512), 0, stream>>>(x, wr, bias, out);
    }
}

// Round 4
// 287.561 us; speedup vs baseline: 3.8142x; 3.8142x over previous
//
#include <hip/hip_runtime.h>
#include <cstdint>
#include <cstddef>

// Conv2d 3x3 s1 p1: N=16, CI=64, CO=128, H=W=224, fp32 in/out.
// v4: identical to v3 except conv2 __launch_bounds__(512,2) — v3's (512,4)
// capped the unified register budget at 128/wave and spilled the 112-float
// accumulator tile to scratch (VGPR_Count=64, WRITE 7x output, FETCH 6x ideal).

typedef short bf16x8 __attribute__((ext_vector_type(8)));
typedef float f32x4 __attribute__((ext_vector_type(4)));

#define N_ 16
#define CI_ 64
#define CO_ 128
#define H_ 224
#define W_ 224
#define HW_ (H_ * W_)

// xp strides in shorts
#define WP_ 226
#define CBS_ 1808ULL        // WP_*8
#define HPS_ 14464ULL       // 8*CBS_
#define NS_ 3268864ULL      // 226*HPS_

__device__ __forceinline__ unsigned short f2bf(float f) {
    unsigned u = __builtin_bit_cast(unsigned, f);
    u += 0x7FFFu + ((u >> 16) & 1u);   // round-to-nearest-even
    return (unsigned short)(u >> 16);
}

// weight [CO][CI][3][3] fp32 -> wr[t][co][ci] bf16  (t = kh*3+kw)
__global__ void prep_weight(const float* __restrict__ w, unsigned short* __restrict__ wr) {
    int i = blockIdx.x * 256 + threadIdx.x;          // i = t*8192 + co*64 + ci
    if (i >= 9 * CO_ * CI_) return;
    int ci = i & 63;
    int co = (i >> 6) & 127;
    int t  = i >> 13;
    wr[i] = f2bf(w[(co * CI_ + ci) * 9 + t]);
}

// x[n][ci][h][w] fp32 -> xp[n][hp][cb][wp][c8] bf16, halos (hp 0/225, wp 0/225) zero.
__global__ __launch_bounds__(256) void prep_x(const float* __restrict__ x,
                                              unsigned short* __restrict__ xp) {
    int b = blockIdx.x;                 // 16*226
    int n = b / 226, hp = b - n * 226;
    int tid = threadIdx.x;
    unsigned short* row = xp + (size_t)n * NS_ + (size_t)hp * HPS_;
    if (hp == 0 || hp == 225) {
        #pragma unroll
        for (int k = 0; k < 8; ++k) {
            int i = k * 256 + tid;
            if (i < 1808) ((uint4*)row)[i] = make_uint4(0, 0, 0, 0);
        }
        return;
    }
    int h = hp - 1;
    const float* xb = x + (size_t)n * CI_ * HW_ + (size_t)h * W_;
    for (int k = 0; k < 7; ++k) {
        int item = k * 256 + tid;       // 1792 = 8cb * 224w
        int w = item % 224;
        int cb = item / 224;
        unsigned r[4];
        #pragma unroll
        for (int c = 0; c < 4; ++c) {
            float lo = xb[(size_t)(cb * 8 + 2 * c) * HW_ + w];
            float hi = xb[(size_t)(cb * 8 + 2 * c + 1) * HW_ + w];
            r[c] = (unsigned)f2bf(lo) | ((unsigned)f2bf(hi) << 16);
        }
        *(uint4*)(row + (size_t)cb * CBS_ + (size_t)(w + 1) * 8) = make_uint4(r[0], r[1], r[2], r[3]);
    }
    if (tid < 16) {
        int cb = tid >> 1, wp = (tid & 1) * 225;
        *(uint4*)(row + (size_t)cb * CBS_ + (size_t)wp * 8) = make_uint4(0, 0, 0, 0);
    }
}

// Main: one WG (512 thr, 8 waves) -> out[n][0:128][h0:h0+2][0:224].
// (512,2): 256-reg unified budget -> acc tile stays in registers (no spill).
__global__ __launch_bounds__(512, 2) void conv2(
    const unsigned short* __restrict__ xp, const unsigned short* __restrict__ wr,
    const float* __restrict__ bias, float* __restrict__ out)
{
    // compute phase:  xs[r(4)][cbl(4)][wp(226)][8 ci] bf16 = 57,856 B
    // epilogue phase: reused as float lf[8 waves][1808]   = 57,856 B
    __shared__ __align__(16) unsigned short xs[4 * 4 * 226 * 8];

    int bid = blockIdx.x;
    int swz = (bid & 7) * 224 + (bid >> 3);    // bijective: 1792 = 8*224
    int n = swz / 112;
    int hblk = swz - n * 112;
    int h0 = hblk * 2;

    int tid = threadIdx.x, lane = tid & 63, wid = tid >> 6;
    int hr = wid & 1, nh = (wid >> 1) & 1, mh = wid >> 2;
    int lrow = lane & 15, lk = lane >> 4;

    f32x4 acc[4][7];
    #pragma unroll
    for (int a = 0; a < 4; ++a)
        #pragma unroll
        for (int b2 = 0; b2 < 7; ++b2)
            #pragma unroll
            for (int k = 0; k < 4; ++k)
                acc[a][b2][k] = 0.0f;

    const unsigned short* xpn = xp + (size_t)n * NS_;

    for (int ch = 0; ch < 2; ++ch) {
        if (ch) __syncthreads();
        // ---- stage via global_load_lds: 16 runs of 226 x 16B, linear LDS ----
        #pragma unroll
        for (int rr = 0; rr < 2; ++rr) {
            int run = wid * 2 + rr;            // 0..15
            int r = run >> 2, cbl = run & 3;
            const unsigned short* src = xpn + (size_t)(h0 + r) * HPS_ + (size_t)(ch * 4 + cbl) * CBS_;
            unsigned short* dst = &xs[(size_t)(r * 4 + cbl) * (226 * 8)];
            #pragma unroll
            for (int c = 0; c < 4; ++c) {
                int chunk = c * 64 + lane;
                if (chunk < 226)
                    __builtin_amdgcn_global_load_lds(
                        (const __attribute__((address_space(1))) void*)(src + (size_t)chunk * 8),
                        (__attribute__((address_space(3))) void*)(dst + c * 512),
                        16, 0, 0);
            }
        }
        __syncthreads();

        // ---- 9 taps x K=32 ----
        #pragma unroll
        for (int t = 0; t < 9; ++t) {
            int kh = t / 3, kw = t - kh * 3;
            bf16x8 afr[4];
            #pragma unroll
            for (int mf = 0; mf < 4; ++mf) {
                size_t ai = ((size_t)(t * 128 + mh * 64 + mf * 16 + lrow)) * 64
                          + (size_t)(ch * 32 + lk * 8);
                afr[mf] = *(const bf16x8*)(wr + ai);
            }
            int rbase = ((hr + kh) * 4 + lk) * 226;
            int wpb = nh * 112 + lrow + kw;
            #pragma unroll
            for (int nf = 0; nf < 7; ++nf) {
                bf16x8 bfr = *(const bf16x8*)(&xs[(size_t)(rbase + wpb + nf * 16) * 8]);
                #pragma unroll
                for (int mf = 0; mf < 4; ++mf)
                    acc[mf][nf] = __builtin_amdgcn_mfma_f32_16x16x32_bf16(
                        afr[mf], bfr, acc[mf][nf], 0, 0, 0);
            }
        }
    }

    // ---- epilogue: per-wave LDS transpose -> contiguous float4 stores ----
    // wave region: lf[wid*1808 .. +1808) floats (7232 B, disjoint per wave).
    // layout: [lk(4) stride 452][r(4) stride 112][w_local(112)]
    __syncthreads();                       // all MFMA reads of xs done
    float* lf = (float*)xs;
    int h = h0 + hr;
    #pragma unroll
    for (int mf = 0; mf < 4; ++mf) {
        float bv[4];
        #pragma unroll
        for (int r = 0; r < 4; ++r)
            bv[r] = bias[mh * 64 + mf * 16 + lk * 4 + r];
        // write phase (wave-local; DS ops in-order per wave, no barrier needed)
        float* wbase = lf + wid * 1808 + lk * 452 + lrow;
        #pragma unroll
        for (int r = 0; r < 4; ++r)
            #pragma unroll
            for (int nf = 0; nf < 7; ++nf)
                wbase[r * 112 + nf * 16] = acc[mf][nf][r] + bv[r];
        // read + store phase: 7 x 64-lane float4 = contiguous full-line writes
        #pragma unroll
        for (int j = 0; j < 7; ++j) {
            int idx4 = j * 64 + lane;          // 0..447 (448 float4 per wave)
            int col = idx4 / 28;               // co_local 0..15
            int w4  = idx4 - col * 28;         // 0..27
            f32x4 v = *(const f32x4*)(lf + wid * 1808 + (col >> 2) * 452 + (col & 3) * 112 + w4 * 4);
            size_t ob = (((size_t)n * CO_ + mh * 64 + mf * 16 + col) * H_ + h) * W_
                      + nh * 112 + w4 * 4;
            *(f32x4*)(out + ob) = v;
        }
    }
}

// ---------------- round-1 fallback (used only if ws_size is small) ----------------
__global__ __launch_bounds__(512, 2) void conv_mfma(
    const float* __restrict__ x, const unsigned short* __restrict__ wr,
    const float* __restrict__ bias, float* __restrict__ out)
{
    __shared__ unsigned short xs[4 * 4 * 226 * 8];
    int bid = blockIdx.x;
    int swz = (bid & 7) * 224 + (bid >> 3);
    int n = swz / 112;
    int hblk = swz - n * 112;
    int h0 = hblk * 2;
    int tid = threadIdx.x;
    int lane = tid & 63;
    int wid = tid >> 6;
    int hr = wid & 1, nh = (wid >> 1) & 1, mh = wid >> 2;
    int lrow = lane & 15, lk = lane >> 4;

    f32x4 acc[4][7];
    #pragma unroll
    for (int a = 0; a < 4; ++a)
        #pragma unroll
        for (int b = 0; b < 7; ++b)
            #pragma unroll
            for (int k = 0; k < 4; ++k)
                acc[a][b][k] = 0.0f;

    for (int ch = 0; ch < 2; ++ch) {
        if (ch) __syncthreads();
        const float* xb = x + ((size_t)n * CI_ + (size_t)ch * 32) * HW_;
        int wcol = tid % 224;
        int rem = tid / 224;
        for (int it = 0; it < 7; ++it) {
            float v[8]; int bi[8];
            #pragma unroll
            for (int u = 0; u < 8; ++u) {
                int ciL = rem & 31;
                int r4 = rem >> 5;
                int hh = h0 - 1 + r4;
                float val = 0.0f;
                if ((unsigned)hh < (unsigned)H_)
                    val = xb[(size_t)ciL * HW_ + (size_t)hh * W_ + wcol];
                v[u] = val;
                bi[u] = (((r4 << 2) + (ciL >> 3)) * 226 + wcol + 1) * 8 + (ciL & 7);
                wcol += 64; rem += 2;
                if (wcol >= 224) { wcol -= 224; rem += 1; }
            }
            #pragma unroll
            for (int u = 0; u < 8; ++u)
                xs[bi[u]] = f2bf(v[u]);
        }
        if (tid < 256) {
            int wp = (tid & 1) * 225;
            int ciL = (tid >> 1) & 31;
            int r4 = tid >> 6;
            xs[(((r4 << 2) + (ciL >> 3)) * 226 + wp) * 8 + (ciL & 7)] = 0;
        }
        __syncthreads();

        #pragma unroll
        for (int t = 0; t < 9; ++t) {
            int kh = t / 3, kw = t - kh * 3;
            bf16x8 afr[4];
            #pragma unroll
            for (int mf = 0; mf < 4; ++mf) {
                size_t ai = ((size_t)(t * 128 + mh * 64 + mf * 16 + lrow)) * 64
                          + (size_t)(ch * 32 + lk * 8);
                afr[mf] = *(const bf16x8*)(wr + ai);
            }
            int rbase = ((hr + kh) * 4 + lk) * 226;
            int wpb = nh * 112 + lrow + kw;
            #pragma unroll
            for (int nf = 0; nf < 7; ++nf) {
                bf16x8 bfr = *(const bf16x8*)(&xs[(size_t)(rbase + wpb + nf * 16) * 8]);
                #pragma unroll
                for (int mf = 0; mf < 4; ++mf)
                    acc[mf][nf] = __builtin_amdgcn_mfma_f32_16x16x32_bf16(
                        afr[mf], bfr, acc[mf][nf], 0, 0, 0);
            }
        }
    }

    int h = h0 + hr;
    #pragma unroll
    for (int mf = 0; mf < 4; ++mf) {
        #pragma unroll
        for (int r = 0; r < 4; ++r) {
            int co = mh * 64 + mf * 16 + lk * 4 + r;
            float bv = bias[co];
            size_t ob = (((size_t)n * CO_ + co) * H_ + h) * W_ + nh * 112 + lrow;
            #pragma unroll
            for (int nf = 0; nf < 7; ++nf)
                out[ob + (size_t)nf * 16] = acc[mf][nf][r] + bv;
        }
    }
}

extern "C" void kernel_launch(void* const* d_in, const int* in_sizes, int n_in,
                              void* d_out, int out_size, void* d_ws, size_t ws_size,
                              hipStream_t stream) {
    const float* x    = (const float*)d_in[0];
    const float* w    = (const float*)d_in[1];
    const float* bias = (const float*)d_in[2];
    float* out = (float*)d_out;
    unsigned short* wr = (unsigned short*)d_ws;          // 147,456 B
    const size_t xp_bytes = (size_t)N_ * NS_ * 2;        // 104,603,648 B
    const size_t need = 147456 + xp_bytes;

    prep_weight<<<dim3(288), dim3(256), 0, stream>>>(w, wr);
    if (ws_size >= need) {
        unsigned short* xp = wr + 73728;                 // +147,456 B
        prep_x<<<dim3(16 * 226), dim3(256), 0, stream>>>(x, xp);
        conv2<<<dim3(16 * 112), dim3(512), 0, stream>>>(xp, wr, bias, out);
    } else {
        conv_mfma<<<dim3(16 * 112), dim3(512), 0, stream>>>(x, wr, bias, out);
    }
}

// Round 5
// 286.524 us; speedup vs baseline: 3.8280x; 1.0036x over previous
//
#include <hip/hip_runtime.h>
#include <cstdint>
#include <cstddef>

// Conv2d 3x3 s1 p1: N=16, CI=64, CO=128, H=W=224, fp32 in/out.
// v5: w-split tiling. Block = 256 thr (4 waves) -> out[n][0:128][h0:h0+2][wseg*112 +: 112].
// Full 64-ci stage (58 KB LDS) in ONE shot -> single barrier, no per-half restage;
// 2 blocks/CU co-resident so one block's MFMA phase hides the other's staging drain.

typedef short bf16x8 __attribute__((ext_vector_type(8)));
typedef float f32x4 __attribute__((ext_vector_type(4)));

#define N_ 16
#define CI_ 64
#define CO_ 128
#define H_ 224
#define W_ 224
#define HW_ (H_ * W_)

// xp strides in shorts
#define WP_ 226
#define CBS_ 1808ULL        // WP_*8
#define HPS_ 14464ULL       // 8*CBS_
#define NS_ 3268864ULL      // 226*HPS_

__device__ __forceinline__ unsigned short f2bf(float f) {
    unsigned u = __builtin_bit_cast(unsigned, f);
    u += 0x7FFFu + ((u >> 16) & 1u);   // round-to-nearest-even
    return (unsigned short)(u >> 16);
}

// weight [CO][CI][3][3] fp32 -> wr[t][co][ci] bf16  (t = kh*3+kw)
__global__ void prep_weight(const float* __restrict__ w, unsigned short* __restrict__ wr) {
    int i = blockIdx.x * 256 + threadIdx.x;          // i = t*8192 + co*64 + ci
    if (i >= 9 * CO_ * CI_) return;
    int ci = i & 63;
    int co = (i >> 6) & 127;
    int t  = i >> 13;
    wr[i] = f2bf(w[(co * CI_ + ci) * 9 + t]);
}

// x[n][ci][h][w] fp32 -> xp[n][hp][cb][wp][c8] bf16, halos (hp 0/225, wp 0/225) zero.
__global__ __launch_bounds__(256) void prep_x(const float* __restrict__ x,
                                              unsigned short* __restrict__ xp) {
    int b = blockIdx.x;                 // 16*226
    int n = b / 226, hp = b - n * 226;
    int tid = threadIdx.x;
    unsigned short* row = xp + (size_t)n * NS_ + (size_t)hp * HPS_;
    if (hp == 0 || hp == 225) {
        #pragma unroll
        for (int k = 0; k < 8; ++k) {
            int i = k * 256 + tid;
            if (i < 1808) ((uint4*)row)[i] = make_uint4(0, 0, 0, 0);
        }
        return;
    }
    int h = hp - 1;
    const float* xb = x + (size_t)n * CI_ * HW_ + (size_t)h * W_;
    for (int k = 0; k < 7; ++k) {
        int item = k * 256 + tid;       // 1792 = 8cb * 224w
        int w = item % 224;
        int cb = item / 224;
        unsigned r[4];
        #pragma unroll
        for (int c = 0; c < 4; ++c) {
            float lo = xb[(size_t)(cb * 8 + 2 * c) * HW_ + w];
            float hi = xb[(size_t)(cb * 8 + 2 * c + 1) * HW_ + w];
            r[c] = (unsigned)f2bf(lo) | ((unsigned)f2bf(hi) << 16);
        }
        *(uint4*)(row + (size_t)cb * CBS_ + (size_t)(w + 1) * 8) = make_uint4(r[0], r[1], r[2], r[3]);
    }
    if (tid < 16) {
        int cb = tid >> 1, wp = (tid & 1) * 225;
        *(uint4*)(row + (size_t)cb * CBS_ + (size_t)wp * 8) = make_uint4(0, 0, 0, 0);
    }
}

// Main v5: block (256 thr, 4 waves) -> out[n][0:128][h0:h0+2][wseg*112 +: 112].
// Waves: hr = wid&1 (h row), mh = wid>>1 (co half). Wave tile 64co x 112w.
__global__ __launch_bounds__(256, 2) void conv2(
    const unsigned short* __restrict__ xp, const unsigned short* __restrict__ wr,
    const float* __restrict__ bias, float* __restrict__ out)
{
    // compute phase:  xs[r(4)][cb(8)][wp(114)][8ci] bf16 = 58,368 B  (linear in idx)
    // epilogue phase: reused as float lf[4 waves][1808]  = 28,928 B
    __shared__ __align__(16) unsigned short xs[4 * 8 * 114 * 8];

    int bid = blockIdx.x;
    int swz = (bid & 7) * 448 + (bid >> 3);    // bijective: 3584 = 8*448
    int n = swz / 224;
    int r2 = swz - n * 224;
    int hblk = r2 >> 1;
    int wseg = r2 & 1;
    int h0 = hblk * 2;

    int tid = threadIdx.x, lane = tid & 63, wid = tid >> 6;
    int hr = wid & 1, mh = wid >> 1;
    int lrow = lane & 15, lk = lane >> 4;

    f32x4 acc[4][7];
    #pragma unroll
    for (int a = 0; a < 4; ++a)
        #pragma unroll
        for (int b2 = 0; b2 < 7; ++b2)
            #pragma unroll
            for (int k = 0; k < 4; ++k)
                acc[a][b2][k] = 0.0f;

    const unsigned short* xpn = xp + (size_t)n * NS_;

    // ---- stage ALL 4 rows x 8 cb x 114 wp in one shot (3648 x 16B chunks) ----
    // chunk idx -> wp = idx%114, rc = idx/114 (r = rc>>3, cb = rc&7); LDS linear at idx*16B.
    #pragma unroll
    for (int it = 0; it < 14; ++it) {
        int idx = it * 256 + tid;
        int wp = idx % 114;
        int rc = idx / 114;
        const unsigned short* src = xpn + (size_t)(h0 + (rc >> 3)) * HPS_
                                  + (size_t)(rc & 7) * CBS_ + (size_t)(wseg * 112 + wp) * 8;
        __builtin_amdgcn_global_load_lds(
            (const __attribute__((address_space(1))) void*)src,
            (__attribute__((address_space(3))) void*)(xs + (size_t)idx * 8),
            16, 0, 0);
    }
    if (tid < 64) {
        int idx = 3584 + tid;
        int wp = idx % 114;
        int rc = idx / 114;
        const unsigned short* src = xpn + (size_t)(h0 + (rc >> 3)) * HPS_
                                  + (size_t)(rc & 7) * CBS_ + (size_t)(wseg * 112 + wp) * 8;
        __builtin_amdgcn_global_load_lds(
            (const __attribute__((address_space(1))) void*)src,
            (__attribute__((address_space(3))) void*)(xs + (size_t)idx * 8),
            16, 0, 0);
    }
    __syncthreads();   // one drain+barrier for the whole K loop

    // ---- 2 ci-halves x 9 taps, no barriers ----
    #pragma unroll
    for (int ch = 0; ch < 2; ++ch) {
        #pragma unroll
        for (int t = 0; t < 9; ++t) {
            int kh = t / 3, kw = t - kh * 3;
            bf16x8 afr[4];
            #pragma unroll
            for (int mf = 0; mf < 4; ++mf) {
                size_t ai = ((size_t)(t * 128 + mh * 64 + mf * 16 + lrow)) * 64
                          + (size_t)(ch * 32 + lk * 8);
                afr[mf] = *(const bf16x8*)(wr + ai);
            }
            int rbase = ((hr + kh) * 8 + ch * 4 + lk) * 114;
            int wpb = lrow + kw;
            #pragma unroll
            for (int nf = 0; nf < 7; ++nf) {
                bf16x8 bfr = *(const bf16x8*)(&xs[(size_t)(rbase + wpb + nf * 16) * 8]);
                #pragma unroll
                for (int mf = 0; mf < 4; ++mf)
                    acc[mf][nf] = __builtin_amdgcn_mfma_f32_16x16x32_bf16(
                        afr[mf], bfr, acc[mf][nf], 0, 0, 0);
            }
        }
    }

    // ---- epilogue: per-wave LDS transpose -> contiguous float4 stores ----
    // wave region: lf[wid*1808 .. +1808) floats; layout [lk(4) s452][r(4) s112][w(112)]
    __syncthreads();                       // all MFMA reads of xs done
    float* lf = (float*)xs;
    int h = h0 + hr;
    #pragma unroll
    for (int mf = 0; mf < 4; ++mf) {
        float bv[4];
        #pragma unroll
        for (int r = 0; r < 4; ++r)
            bv[r] = bias[mh * 64 + mf * 16 + lk * 4 + r];
        float* wbase = lf + wid * 1808 + lk * 452 + lrow;
        #pragma unroll
        for (int r = 0; r < 4; ++r)
            #pragma unroll
            for (int nf = 0; nf < 7; ++nf)
                wbase[r * 112 + nf * 16] = acc[mf][nf][r] + bv[r];
        // wave-local: DS ops in-order per wave, no barrier needed before readback
        #pragma unroll
        for (int j = 0; j < 7; ++j) {
            int idx4 = j * 64 + lane;          // 448 float4 per wave
            int col = idx4 / 28;               // co_local 0..15
            int w4  = idx4 - col * 28;         // 0..27
            f32x4 v = *(const f32x4*)(lf + wid * 1808 + (col >> 2) * 452 + (col & 3) * 112 + w4 * 4);
            size_t ob = (((size_t)n * CO_ + mh * 64 + mf * 16 + col) * H_ + h) * W_
                      + wseg * 112 + w4 * 4;
            *(f32x4*)(out + ob) = v;
        }
    }
}

// ---------------- round-1 fallback (used only if ws_size is small) ----------------
__global__ __launch_bounds__(512, 2) void conv_mfma(
    const float* __restrict__ x, const unsigned short* __restrict__ wr,
    const float* __restrict__ bias, float* __restrict__ out)
{
    __shared__ unsigned short xs[4 * 4 * 226 * 8];
    int bid = blockIdx.x;
    int swz = (bid & 7) * 224 + (bid >> 3);
    int n = swz / 112;
    int hblk = swz - n * 112;
    int h0 = hblk * 2;
    int tid = threadIdx.x;
    int lane = tid & 63;
    int wid = tid >> 6;
    int hr = wid & 1, nh = (wid >> 1) & 1, mh = wid >> 2;
    int lrow = lane & 15, lk = lane >> 4;

    f32x4 acc[4][7];
    #pragma unroll
    for (int a = 0; a < 4; ++a)
        #pragma unroll
        for (int b = 0; b < 7; ++b)
            #pragma unroll
            for (int k = 0; k < 4; ++k)
                acc[a][b][k] = 0.0f;

    for (int ch = 0; ch < 2; ++ch) {
        if (ch) __syncthreads();
        const float* xb = x + ((size_t)n * CI_ + (size_t)ch * 32) * HW_;
        int wcol = tid % 224;
        int rem = tid / 224;
        for (int it = 0; it < 7; ++it) {
            float v[8]; int bi[8];
            #pragma unroll
            for (int u = 0; u < 8; ++u) {
                int ciL = rem & 31;
                int r4 = rem >> 5;
                int hh = h0 - 1 + r4;
                float val = 0.0f;
                if ((unsigned)hh < (unsigned)H_)
                    val = xb[(size_t)ciL * HW_ + (size_t)hh * W_ + wcol];
                v[u] = val;
                bi[u] = (((r4 << 2) + (ciL >> 3)) * 226 + wcol + 1) * 8 + (ciL & 7);
                wcol += 64; rem += 2;
                if (wcol >= 224) { wcol -= 224; rem += 1; }
            }
            #pragma unroll
            for (int u = 0; u < 8; ++u)
                xs[bi[u]] = f2bf(v[u]);
        }
        if (tid < 256) {
            int wp = (tid & 1) * 225;
            int ciL = (tid >> 1) & 31;
            int r4 = tid >> 6;
            xs[(((r4 << 2) + (ciL >> 3)) * 226 + wp) * 8 + (ciL & 7)] = 0;
        }
        __syncthreads();

        #pragma unroll
        for (int t = 0; t < 9; ++t) {
            int kh = t / 3, kw = t - kh * 3;
            bf16x8 afr[4];
            #pragma unroll
            for (int mf = 0; mf < 4; ++mf) {
                size_t ai = ((size_t)(t * 128 + mh * 64 + mf * 16 + lrow)) * 64
                          + (size_t)(ch * 32 + lk * 8);
                afr[mf] = *(const bf16x8*)(wr + ai);
            }
            int rbase = ((hr + kh) * 4 + lk) * 226;
            int wpb = nh * 112 + lrow + kw;
            #pragma unroll
            for (int nf = 0; nf < 7; ++nf) {
                bf16x8 bfr = *(const bf16x8*)(&xs[(size_t)(rbase + wpb + nf * 16) * 8]);
                #pragma unroll
                for (int mf = 0; mf < 4; ++mf)
                    acc[mf][nf] = __builtin_amdgcn_mfma_f32_16x16x32_bf16(
                        afr[mf], bfr, acc[mf][nf], 0, 0, 0);
            }
        }
    }

    int h = h0 + hr;
    #pragma unroll
    for (int mf = 0; mf < 4; ++mf) {
        #pragma unroll
        for (int r = 0; r < 4; ++r) {
            int co = mh * 64 + mf * 16 + lk * 4 + r;
            float bv = bias[co];
            size_t ob = (((size_t)n * CO_ + co) * H_ + h) * W_ + nh * 112 + lrow;
            #pragma unroll
            for (int nf = 0; nf < 7; ++nf)
                out[ob + (size_t)nf * 16] = acc[mf][nf][r] + bv;
        }
    }
}

extern "C" void kernel_launch(void* const* d_in, const int* in_sizes, int n_in,
                              void* d_out, int out_size, void* d_ws, size_t ws_size,
                              hipStream_t stream) {
    const float* x    = (const float*)d_in[0];
    const float* w    = (const float*)d_in[1];
    const float* bias = (const float*)d_in[2];
    float* out = (float*)d_out;
    unsigned short* wr = (unsigned short*)d_ws;          // 147,456 B
    const size_t xp_bytes = (size_t)N_ * NS_ * 2;        // 104,603,648 B
    const size_t need = 147456 + xp_bytes;

    prep_weight<<<dim3(288), dim3(256), 0, stream>>>(w, wr);
    if (ws_size >= need) {
        unsigned short* xp = wr + 73728;                 // +147,456 B
        prep_x<<<dim3(16 * 226), dim3(256), 0, stream>>>(x, xp);
        conv2<<<dim3(16 * 112 * 2), dim3(256), 0, stream>>>(xp, wr, bias, out);
    } else {
        conv_mfma<<<dim3(16 * 112), dim3(512), 0, stream>>>(x, wr, bias, out);
    }
}

// Round 6
// 243.759 us; speedup vs baseline: 4.4996x; 1.1754x over previous
//
#include <hip/hip_runtime.h>
#include <cstdint>
#include <cstddef>

// Conv2d 3x3 s1 p1: N=16, CI=64, CO=128, H=W=224, fp32 in/out.
// v6: persistent-strip conv3. Block (512 thr) owns out[n][0:128][strip*28 +:28][wseg*112 +:112],
// rolling 6-slot LDS row ring (hp mod 6), per-step: prefetch-next (global_load_lds) ->
// compute -> epilogue -> barrier. Prefetch drains for free under compute; xp staged once.
// Dynamic LDS 145,408 B (needs hipFuncSetAttribute; falls back to v5 conv2 if denied).

typedef short bf16x8 __attribute__((ext_vector_type(8)));
typedef float f32x4 __attribute__((ext_vector_type(4)));

#define N_ 16
#define CI_ 64
#define CO_ 128
#define H_ 224
#define W_ 224
#define HW_ (H_ * W_)

// xp strides in shorts
#define WP_ 226
#define CBS_ 1808ULL        // WP_*8
#define HPS_ 14464ULL       // 8*CBS_
#define NS_ 3268864ULL      // 226*HPS_

#define ROWBUF_SHORTS 7296  // 8cb * 114wp * 8ci
#define CONV3_LDS 145408    // 6*7296*2 + 8*1808*4

__device__ __forceinline__ unsigned short f2bf(float f) {
    unsigned u = __builtin_bit_cast(unsigned, f);
    u += 0x7FFFu + ((u >> 16) & 1u);   // round-to-nearest-even
    return (unsigned short)(u >> 16);
}

// weight [CO][CI][3][3] fp32 -> wr[t][co][ci] bf16  (t = kh*3+kw)
__global__ void prep_weight(const float* __restrict__ w, unsigned short* __restrict__ wr) {
    int i = blockIdx.x * 256 + threadIdx.x;          // i = t*8192 + co*64 + ci
    if (i >= 9 * CO_ * CI_) return;
    int ci = i & 63;
    int co = (i >> 6) & 127;
    int t  = i >> 13;
    wr[i] = f2bf(w[(co * CI_ + ci) * 9 + t]);
}

// x[n][ci][h][w] fp32 -> xp[n][hp][cb][wp][c8] bf16, halos (hp 0/225, wp 0/225) zero.
__global__ __launch_bounds__(256) void prep_x(const float* __restrict__ x,
                                              unsigned short* __restrict__ xp) {
    int b = blockIdx.x;                 // 16*226
    int n = b / 226, hp = b - n * 226;
    int tid = threadIdx.x;
    unsigned short* row = xp + (size_t)n * NS_ + (size_t)hp * HPS_;
    if (hp == 0 || hp == 225) {
        #pragma unroll
        for (int k = 0; k < 8; ++k) {
            int i = k * 256 + tid;
            if (i < 1808) ((uint4*)row)[i] = make_uint4(0, 0, 0, 0);
        }
        return;
    }
    int h = hp - 1;
    const float* xb = x + (size_t)n * CI_ * HW_ + (size_t)h * W_;
    for (int k = 0; k < 7; ++k) {
        int item = k * 256 + tid;       // 1792 = 8cb * 224w
        int w = item % 224;
        int cb = item / 224;
        unsigned r[4];
        #pragma unroll
        for (int c = 0; c < 4; ++c) {
            float lo = xb[(size_t)(cb * 8 + 2 * c) * HW_ + w];
            float hi = xb[(size_t)(cb * 8 + 2 * c + 1) * HW_ + w];
            r[c] = (unsigned)f2bf(lo) | ((unsigned)f2bf(hi) << 16);
        }
        *(uint4*)(row + (size_t)cb * CBS_ + (size_t)(w + 1) * 8) = make_uint4(r[0], r[1], r[2], r[3]);
    }
    if (tid < 16) {
        int cb = tid >> 1, wp = (tid & 1) * 225;
        *(uint4*)(row + (size_t)cb * CBS_ + (size_t)wp * 8) = make_uint4(0, 0, 0, 0);
    }
}

// v6 main: persistent strip. 8 waves: hr = wid&1 (out row), mq = wid>>1 (co quarter).
// Wave tile 32co x 112w, acc[2][7] f32x4.
__global__ __launch_bounds__(512, 2) void conv3(
    const unsigned short* __restrict__ xp, const unsigned short* __restrict__ wr,
    const float* __restrict__ bias, float* __restrict__ out)
{
    extern __shared__ __align__(16) unsigned short ring[];  // [6][7296] shorts + bounce floats
    float* bounce = (float*)ring + 6 * ROWBUF_SHORTS / 2;   // 21888 floats in

    int bid = blockIdx.x;
    int swz = (bid & 7) * 32 + (bid >> 3);     // bijective over 256, XCD-chunked
    int n = swz >> 4;
    int rem = swz & 15;
    int wseg = rem & 1;
    int strip = rem >> 1;
    int ho0 = strip * 28;

    int tid = threadIdx.x, lane = tid & 63, wid = tid >> 6;
    int hr = wid & 1, mq = wid >> 1;
    int lrow = lane & 15, lk = lane >> 4;

    const unsigned short* xpn = xp + (size_t)n * NS_;

    // stage one xp row (912 x 16B chunks) into its ring slot; dst linear in tid.
    auto stage_row = [&](int hp) {
        const unsigned short* srow = xpn + (size_t)hp * HPS_ + (size_t)(wseg * 112) * 8;
        unsigned short* dbase = ring + (size_t)(hp % 6) * ROWBUF_SHORTS;
        int idx = tid;
        {
            int cb = idx / 114, wp = idx - cb * 114;
            __builtin_amdgcn_global_load_lds(
                (const __attribute__((address_space(1))) void*)(srow + (size_t)cb * CBS_ + (size_t)wp * 8),
                (__attribute__((address_space(3))) void*)(dbase + (size_t)idx * 8), 16, 0, 0);
        }
        idx = 512 + tid;
        if (idx < 912) {
            int cb = idx / 114, wp = idx - cb * 114;
            __builtin_amdgcn_global_load_lds(
                (const __attribute__((address_space(1))) void*)(srow + (size_t)cb * CBS_ + (size_t)wp * 8),
                (__attribute__((address_space(3))) void*)(dbase + (size_t)idx * 8), 16, 0, 0);
        }
    };

    // prologue: rows ho0..ho0+3
    stage_row(ho0); stage_row(ho0 + 1); stage_row(ho0 + 2); stage_row(ho0 + 3);
    __syncthreads();

    #pragma unroll 1
    for (int i = 0; i < 14; ++i) {
        int ho = ho0 + 2 * i;

        // 1) prefetch next step's two new rows into the (dead) slots
        if (i < 13) { stage_row(ho + 4); stage_row(ho + 5); }

        // 2) compute: 2 ci-halves x 9 taps on rows ho..ho+3 (staged last step)
        f32x4 acc[2][7];
        #pragma unroll
        for (int a = 0; a < 2; ++a)
            #pragma unroll
            for (int b2 = 0; b2 < 7; ++b2)
                #pragma unroll
                for (int k = 0; k < 4; ++k)
                    acc[a][b2][k] = 0.0f;

        #pragma unroll
        for (int ch = 0; ch < 2; ++ch) {
            #pragma unroll
            for (int t = 0; t < 9; ++t) {
                int kh = t / 3, kw = t - kh * 3;
                bf16x8 afr[2];
                #pragma unroll
                for (int mf = 0; mf < 2; ++mf) {
                    size_t ai = ((size_t)(t * 128 + mq * 32 + mf * 16 + lrow)) * 64
                              + (size_t)(ch * 32 + lk * 8);
                    afr[mf] = *(const bf16x8*)(wr + ai);
                }
                int slot = (ho + hr + kh) % 6;
                int rb = slot * ROWBUF_SHORTS + ((ch * 4 + lk) * 114) * 8;
                int wb = lrow + kw;
                #pragma unroll
                for (int nf = 0; nf < 7; ++nf) {
                    bf16x8 bfr = *(const bf16x8*)(ring + rb + (size_t)(wb + nf * 16) * 8);
                    acc[0][nf] = __builtin_amdgcn_mfma_f32_16x16x32_bf16(afr[0], bfr, acc[0][nf], 0, 0, 0);
                    acc[1][nf] = __builtin_amdgcn_mfma_f32_16x16x32_bf16(afr[1], bfr, acc[1][nf], 0, 0, 0);
                }
            }
        }

        // 3) epilogue: per-wave LDS bounce -> contiguous float4 stores
        float* lf = bounce + wid * 1808;
        int h = ho + hr;
        #pragma unroll
        for (int mf = 0; mf < 2; ++mf) {
            float bv[4];
            #pragma unroll
            for (int r = 0; r < 4; ++r)
                bv[r] = bias[mq * 32 + mf * 16 + lk * 4 + r];
            float* wbase = lf + lk * 452 + lrow;
            #pragma unroll
            for (int r = 0; r < 4; ++r)
                #pragma unroll
                for (int nf = 0; nf < 7; ++nf)
                    wbase[r * 112 + nf * 16] = acc[mf][nf][r] + bv[r];
            // wave-local: DS ops in-order per wave
            #pragma unroll
            for (int j = 0; j < 7; ++j) {
                int idx4 = j * 64 + lane;          // 448 float4 per wave
                int col = idx4 / 28;               // co_local 0..15
                int w4  = idx4 - col * 28;
                f32x4 v = *(const f32x4*)(lf + (col >> 2) * 452 + (col & 3) * 112 + w4 * 4);
                size_t ob = (((size_t)n * CO_ + mq * 32 + mf * 16 + col) * H_ + h) * W_
                          + wseg * 112 + w4 * 4;
                *(f32x4*)(out + ob) = v;
            }
        }

        // 4) one barrier: drains prefetch (covered by compute) + publishes ring
        __syncthreads();
    }
}

// ---------------- v5 conv2 (fallback if dynamic-LDS attribute fails) ----------------
__global__ __launch_bounds__(256, 2) void conv2(
    const unsigned short* __restrict__ xp, const unsigned short* __restrict__ wr,
    const float* __restrict__ bias, float* __restrict__ out)
{
    __shared__ __align__(16) unsigned short xs[4 * 8 * 114 * 8];

    int bid = blockIdx.x;
    int swz = (bid & 7) * 448 + (bid >> 3);
    int n = swz / 224;
    int r2 = swz - n * 224;
    int hblk = r2 >> 1;
    int wseg = r2 & 1;
    int h0 = hblk * 2;

    int tid = threadIdx.x, lane = tid & 63, wid = tid >> 6;
    int hr = wid & 1, mh = wid >> 1;
    int lrow = lane & 15, lk = lane >> 4;

    f32x4 acc[4][7];
    #pragma unroll
    for (int a = 0; a < 4; ++a)
        #pragma unroll
        for (int b2 = 0; b2 < 7; ++b2)
            #pragma unroll
            for (int k = 0; k < 4; ++k)
                acc[a][b2][k] = 0.0f;

    const unsigned short* xpn = xp + (size_t)n * NS_;

    #pragma unroll
    for (int it = 0; it < 14; ++it) {
        int idx = it * 256 + tid;
        int wp = idx % 114;
        int rc = idx / 114;
        const unsigned short* src = xpn + (size_t)(h0 + (rc >> 3)) * HPS_
                                  + (size_t)(rc & 7) * CBS_ + (size_t)(wseg * 112 + wp) * 8;
        __builtin_amdgcn_global_load_lds(
            (const __attribute__((address_space(1))) void*)src,
            (__attribute__((address_space(3))) void*)(xs + (size_t)idx * 8), 16, 0, 0);
    }
    if (tid < 64) {
        int idx = 3584 + tid;
        int wp = idx % 114;
        int rc = idx / 114;
        const unsigned short* src = xpn + (size_t)(h0 + (rc >> 3)) * HPS_
                                  + (size_t)(rc & 7) * CBS_ + (size_t)(wseg * 112 + wp) * 8;
        __builtin_amdgcn_global_load_lds(
            (const __attribute__((address_space(1))) void*)src,
            (__attribute__((address_space(3))) void*)(xs + (size_t)idx * 8), 16, 0, 0);
    }
    __syncthreads();

    #pragma unroll
    for (int ch = 0; ch < 2; ++ch) {
        #pragma unroll
        for (int t = 0; t < 9; ++t) {
            int kh = t / 3, kw = t - kh * 3;
            bf16x8 afr[4];
            #pragma unroll
            for (int mf = 0; mf < 4; ++mf) {
                size_t ai = ((size_t)(t * 128 + mh * 64 + mf * 16 + lrow)) * 64
                          + (size_t)(ch * 32 + lk * 8);
                afr[mf] = *(const bf16x8*)(wr + ai);
            }
            int rbase = ((hr + kh) * 8 + ch * 4 + lk) * 114;
            int wpb = lrow + kw;
            #pragma unroll
            for (int nf = 0; nf < 7; ++nf) {
                bf16x8 bfr = *(const bf16x8*)(&xs[(size_t)(rbase + wpb + nf * 16) * 8]);
                #pragma unroll
                for (int mf = 0; mf < 4; ++mf)
                    acc[mf][nf] = __builtin_amdgcn_mfma_f32_16x16x32_bf16(
                        afr[mf], bfr, acc[mf][nf], 0, 0, 0);
            }
        }
    }

    __syncthreads();
    float* lf = (float*)xs;
    int h = h0 + hr;
    #pragma unroll
    for (int mf = 0; mf < 4; ++mf) {
        float bv[4];
        #pragma unroll
        for (int r = 0; r < 4; ++r)
            bv[r] = bias[mh * 64 + mf * 16 + lk * 4 + r];
        float* wbase = lf + wid * 1808 + lk * 452 + lrow;
        #pragma unroll
        for (int r = 0; r < 4; ++r)
            #pragma unroll
            for (int nf = 0; nf < 7; ++nf)
                wbase[r * 112 + nf * 16] = acc[mf][nf][r] + bv[r];
        #pragma unroll
        for (int j = 0; j < 7; ++j) {
            int idx4 = j * 64 + lane;
            int col = idx4 / 28;
            int w4  = idx4 - col * 28;
            f32x4 v = *(const f32x4*)(lf + wid * 1808 + (col >> 2) * 452 + (col & 3) * 112 + w4 * 4);
            size_t ob = (((size_t)n * CO_ + mh * 64 + mf * 16 + col) * H_ + h) * W_
                      + wseg * 112 + w4 * 4;
            *(f32x4*)(out + ob) = v;
        }
    }
}

// ---------------- round-1 fallback (used only if ws_size is small) ----------------
__global__ __launch_bounds__(512, 2) void conv_mfma(
    const float* __restrict__ x, const unsigned short* __restrict__ wr,
    const float* __restrict__ bias, float* __restrict__ out)
{
    __shared__ unsigned short xs[4 * 4 * 226 * 8];
    int bid = blockIdx.x;
    int swz = (bid & 7) * 224 + (bid >> 3);
    int n = swz / 112;
    int hblk = swz - n * 112;
    int h0 = hblk * 2;
    int tid = threadIdx.x;
    int lane = tid & 63;
    int wid = tid >> 6;
    int hr = wid & 1, nh = (wid >> 1) & 1, mh = wid >> 2;
    int lrow = lane & 15, lk = lane >> 4;

    f32x4 acc[4][7];
    #pragma unroll
    for (int a = 0; a < 4; ++a)
        #pragma unroll
        for (int b = 0; b < 7; ++b)
            #pragma unroll
            for (int k = 0; k < 4; ++k)
                acc[a][b][k] = 0.0f;

    for (int ch = 0; ch < 2; ++ch) {
        if (ch) __syncthreads();
        const float* xb = x + ((size_t)n * CI_ + (size_t)ch * 32) * HW_;
        int wcol = tid % 224;
        int rem = tid / 224;
        for (int it = 0; it < 7; ++it) {
            float v[8]; int bi[8];
            #pragma unroll
            for (int u = 0; u < 8; ++u) {
                int ciL = rem & 31;
                int r4 = rem >> 5;
                int hh = h0 - 1 + r4;
                float val = 0.0f;
                if ((unsigned)hh < (unsigned)H_)
                    val = xb[(size_t)ciL * HW_ + (size_t)hh * W_ + wcol];
                v[u] = val;
                bi[u] = (((r4 << 2) + (ciL >> 3)) * 226 + wcol + 1) * 8 + (ciL & 7);
                wcol += 64; rem += 2;
                if (wcol >= 224) { wcol -= 224; rem += 1; }
            }
            #pragma unroll
            for (int u = 0; u < 8; ++u)
                xs[bi[u]] = f2bf(v[u]);
        }
        if (tid < 256) {
            int wp = (tid & 1) * 225;
            int ciL = (tid >> 1) & 31;
            int r4 = tid >> 6;
            xs[(((r4 << 2) + (ciL >> 3)) * 226 + wp) * 8 + (ciL & 7)] = 0;
        }
        __syncthreads();

        #pragma unroll
        for (int t = 0; t < 9; ++t) {
            int kh = t / 3, kw = t - kh * 3;
            bf16x8 afr[4];
            #pragma unroll
            for (int mf = 0; mf < 4; ++mf) {
                size_t ai = ((size_t)(t * 128 + mh * 64 + mf * 16 + lrow)) * 64
                          + (size_t)(ch * 32 + lk * 8);
                afr[mf] = *(const bf16x8*)(wr + ai);
            }
            int rbase = ((hr + kh) * 4 + lk) * 226;
            int wpb = nh * 112 + lrow + kw;
            #pragma unroll
            for (int nf = 0; nf < 7; ++nf) {
                bf16x8 bfr = *(const bf16x8*)(&xs[(size_t)(rbase + wpb + nf * 16) * 8]);
                #pragma unroll
                for (int mf = 0; mf < 4; ++mf)
                    acc[mf][nf] = __builtin_amdgcn_mfma_f32_16x16x32_bf16(
                        afr[mf], bfr, acc[mf][nf], 0, 0, 0);
            }
        }
    }

    int h = h0 + hr;
    #pragma unroll
    for (int mf = 0; mf < 4; ++mf) {
        #pragma unroll
        for (int r = 0; r < 4; ++r) {
            int co = mh * 64 + mf * 16 + lk * 4 + r;
            float bv = bias[co];
            size_t ob = (((size_t)n * CO_ + co) * H_ + h) * W_ + nh * 112 + lrow;
            #pragma unroll
            for (int nf = 0; nf < 7; ++nf)
                out[ob + (size_t)nf * 16] = acc[mf][nf][r] + bv;
        }
    }
}

extern "C" void kernel_launch(void* const* d_in, const int* in_sizes, int n_in,
                              void* d_out, int out_size, void* d_ws, size_t ws_size,
                              hipStream_t stream) {
    const float* x    = (const float*)d_in[0];
    const float* w    = (const float*)d_in[1];
    const float* bias = (const float*)d_in[2];
    float* out = (float*)d_out;
    unsigned short* wr = (unsigned short*)d_ws;          // 147,456 B
    const size_t xp_bytes = (size_t)N_ * NS_ * 2;        // 104,603,648 B
    const size_t need = 147456 + xp_bytes;

    prep_weight<<<dim3(288), dim3(256), 0, stream>>>(w, wr);
    if (ws_size >= need) {
        unsigned short* xp = wr + 73728;                 // +147,456 B
        prep_x<<<dim3(16 * 226), dim3(256), 0, stream>>>(x, xp);
        hipError_t e = hipFuncSetAttribute(
            reinterpret_cast<const void*>(conv3),
            hipFuncAttributeMaxDynamicSharedMemorySize, CONV3_LDS);
        if (e == hipSuccess) {
            conv3<<<dim3(256), dim3(512), CONV3_LDS, stream>>>(xp, wr, bias, out);
        } else {
            conv2<<<dim3(16 * 112 * 2), dim3(256), 0, stream>>>(xp, wr, bias, out);
        }
    } else {
        conv_mfma<<<dim3(16 * 112), dim3(512), 0, stream>>>(x, wr, bias, out);
    }
}